// Round 1
// baseline (390.455 us; speedup 1.0000x reference)
//
#include <hip/hip_runtime.h>

// Problem constants (from reference): B=8, E=4096, H=32, D=128, L=4095
#define EDIM 4096
#define NB 8
#define NH 32
#define HD 128
#define LCACHE 4095.0f

// -----------------------------------------------------------------------------
// proj_kernel: out[m][b][row] = sum_e x[b][e] * Wm[row][e]
// Batched matvec, memory-bound on W (64MB per matrix, f32).
//
// Lane layout (wave=64): b = lane>>3 (batch 0..7), sub = lane&7.
// Block = 1024 threads = 16 waves; wave w owns e-range [w*256, (w+1)*256).
// Each lane preloads its batch's x slice (8 float4 = 32 VGPR) once per block,
// then streams W rows. Per row: 8 float4 W loads (8-way broadcast across the
// b-groups, 128B distinct bytes per instruction -> exactly 16KB/row fetched),
// 32 FMAs, a 3-stage 8-lane shuffle reduce, and one atomicAdd per output.
// No __syncthreads in the hot loop -> loads pipeline across rows.
// -----------------------------------------------------------------------------
__global__ __launch_bounds__(1024, 4)
void proj_kernel(const float* __restrict__ x,
                 const float* __restrict__ W0,
                 const float* __restrict__ W1,
                 const float* __restrict__ W2,
                 float* __restrict__ out,
                 int total_rows)
{
    const int tid  = threadIdx.x;
    const int lane = tid & 63;
    const int wid  = tid >> 6;       // wave id 0..15
    const int b    = lane >> 3;      // batch 0..7
    const int sub  = lane & 7;       // e-slot within wave

    // x preload: float4 index = b*(E/4) + wid*64 + j*8 + sub
    const float4* x4 = (const float4*)x;
    const int xbase = b * (EDIM / 4) + wid * 64 + sub;
    float4 xr[8];
#pragma unroll
    for (int j = 0; j < 8; ++j)
        xr[j] = x4[xbase + j * 8];

    const int ebase4 = wid * 64 + sub;   // float4 index within a W row

    for (int rg = blockIdx.x; rg < total_rows; rg += gridDim.x) {
        const int m   = rg >> 12;           // rg / 4096 (matrix select)
        const int row = rg & (EDIM - 1);    // rg % 4096
        const float* W = (m == 0) ? W0 : ((m == 1) ? W1 : W2);
        const float4* Wr = (const float4*)(W + (size_t)row * EDIM);

        float acc = 0.0f;
#pragma unroll
        for (int j = 0; j < 8; ++j) {
            float4 w4 = Wr[ebase4 + j * 8];
            acc += w4.x * xr[j].x + w4.y * xr[j].y +
                   w4.z * xr[j].z + w4.w * xr[j].w;
        }

        // reduce across the 8 sub-lanes sharing this (b,row)
        acc += __shfl_xor(acc, 1, 64);
        acc += __shfl_xor(acc, 2, 64);
        acc += __shfl_xor(acc, 4, 64);

        if (sub == 0) {
            atomicAdd(out + ((size_t)m * (NB * EDIM) + (size_t)b * EDIM + row), acc);
        }
    }
}

// -----------------------------------------------------------------------------
// attn_kernel: closed form of the ones-cache attention.
//   s0 = sum(q)/sqrt(D)         (score of every one of the 4095 cache slots)
//   s1 = dot(q,k)/sqrt(D)       (score of the appended position)
//   o_d = (4095*e0 + e1*v_d) / (4095*e0 + e1),  e = exp(s - max)
// One block (128 threads = D) per (b,h).
// -----------------------------------------------------------------------------
__global__ __launch_bounds__(128)
void attn_kernel(const float* __restrict__ qkv, float* __restrict__ o)
{
    const int bh = blockIdx.x;              // b*32 + h
    const int d  = threadIdx.x;             // 0..127
    const int off = (bh >> 5) * EDIM + (bh & 31) * HD + d;

    const float* q = qkv;
    const float* k = qkv + NB * EDIM;
    const float* v = qkv + 2 * NB * EDIM;

    const float qd = q[off];
    const float kd = k[off];
    const float vd = v[off];

    float s1p = qd;
    float s2p = qd * kd;
#pragma unroll
    for (int m = 1; m < 64; m <<= 1) {
        s1p += __shfl_xor(s1p, m, 64);
        s2p += __shfl_xor(s2p, m, 64);
    }

    __shared__ float l1[2], l2[2];
    const int wid = d >> 6;
    if ((d & 63) == 0) { l1[wid] = s1p; l2[wid] = s2p; }
    __syncthreads();

    const float sq  = l1[0] + l1[1];
    const float sqk = l2[0] + l2[1];

    const float scale = 0.08838834764831843f;   // 1/sqrt(128)
    const float s0 = sq  * scale;
    const float s1 = sqk * scale;
    const float mx = fmaxf(s0, s1);
    const float e0 = expf(s0 - mx);
    const float e1 = expf(s1 - mx);
    const float Z  = LCACHE * e0 + e1;

    o[off] = (LCACHE * e0 + e1 * vd) / Z;
}

// -----------------------------------------------------------------------------
// kernel_launch
// d_in: [x (8*1*4096), Wq, Wk, Wv, Wo (each 4096*4096)], all f32.
// d_out: 8*4096 f32.  Workspace layout (floats): q[8][4096], k[..], v[..], o[..]
// -----------------------------------------------------------------------------
extern "C" void kernel_launch(void* const* d_in, const int* in_sizes, int n_in,
                              void* d_out, int out_size, void* d_ws, size_t ws_size,
                              hipStream_t stream)
{
    const float* x  = (const float*)d_in[0];
    const float* Wq = (const float*)d_in[1];
    const float* Wk = (const float*)d_in[2];
    const float* Wv = (const float*)d_in[3];
    const float* Wo = (const float*)d_in[4];
    float* out = (float*)d_out;
    float* qkv = (float*)d_ws;                   // 4 * 8 * 4096 floats = 512KB
    float* obuf = qkv + 3 * NB * EDIM;

    // zero the atomic-accumulated buffers (ws/out are poisoned 0xAA by harness)
    hipMemsetAsync(qkv, 0, (size_t)4 * NB * EDIM * sizeof(float), stream);
    hipMemsetAsync(out, 0, (size_t)NB * EDIM * sizeof(float), stream);

    // q,k,v projections: 3*4096 rows
    proj_kernel<<<512, 1024, 0, stream>>>(x, Wq, Wk, Wv, qkv, 3 * EDIM);

    // attention closed form -> o
    attn_kernel<<<NB * NH, 128, 0, stream>>>(qkv, obuf);

    // out-projection: 4096 rows into d_out
    proj_kernel<<<512, 1024, 0, stream>>>(obuf, Wo, Wo, Wo, out, EDIM);
}